// Round 8
// baseline (54646.558 us; speedup 1.0000x reference)
//
#include <hip/hip_runtime.h>
#include <stdint.h>

#define T_STEPS 101
#define ROWS 1600
#define NTHR 512
#define NBLK 512            /* 2 batches per block, 1024 batches total */
#define G1  10              /* L1: 40 nz  = 10 groups of 4 */
#define G23 13              /* L2/3: 50 nz -> padded 52 = 13 groups */

/* ws byte offsets (all 16B aligned) */
#define W1V_OFF 0
#define W2V_OFF 256000
#define W3V_OFF 588800
#define W1C_OFF 921600
#define W2C_OFF 1049600
#define W3C_OFF 1216000

__device__ __forceinline__ float sigmoidf(float v) { return 1.0f / (1.0f + expf(-v)); }

// ---------------------------------------------------------------------------
// Prep: fixed-length CSR packed as float4 weight groups + uint2 col groups
// (4 u16 pre-scaled byte offsets per uint2). SoA [group][1600] for coalescing.
// L1 offsets scale x8 (float2 table rows), L2/3 scale x2 (u8[2] table rows).
// Padding entries w=0, off=0 (fmaf(0,s,a)==a -> bitwise safe). Ascending col
// order == round-1's verified op order.
// ---------------------------------------------------------------------------
__global__ void prep_kernel(const float* __restrict__ W1, const float* __restrict__ W2,
                            const float* __restrict__ W3, uint8_t* __restrict__ ws) {
  int gid = blockIdx.x * blockDim.x + threadIdx.x;
  if (gid >= 3 * ROWS) return;
  int l = gid / ROWS, r = gid - l * ROWS;
  const float* W; int in_f, knz, G, scale; float4* wv; uint2* wc;
  if (l == 0)      { W = W1; in_f = 320; knz = 40; G = G1;  scale = 8;
                     wv = (float4*)(ws + W1V_OFF); wc = (uint2*)(ws + W1C_OFF); }
  else if (l == 1) { W = W2; in_f = 400; knz = 50; G = G23; scale = 2;
                     wv = (float4*)(ws + W2V_OFF); wc = (uint2*)(ws + W2C_OFF); }
  else             { W = W3; in_f = 400; knz = 50; G = G23; scale = 2;
                     wv = (float4*)(ws + W3V_OFF); wc = (uint2*)(ws + W3C_OFF); }
  float wl[52]; uint32_t cl[52];
  int cnt = 0;
  for (int col = 0; col < in_f; ++col) {
    float w = W[(size_t)r * in_f + col];
    if (w != 0.0f && cnt < knz) { wl[cnt] = w; cl[cnt] = (uint32_t)(col * scale); ++cnt; }
  }
  for (; cnt < G * 4; ++cnt) { wl[cnt] = 0.0f; cl[cnt] = 0u; }
  for (int g = 0; g < G; ++g) {
    wv[g * ROWS + r] = make_float4(wl[4*g], wl[4*g+1], wl[4*g+2], wl[4*g+3]);
    wc[g * ROWS + r] = make_uint2(cl[4*g] | (cl[4*g+1] << 16),
                                  cl[4*g+2] | (cl[4*g+3] << 16));
  }
}

// ---------------------------------------------------------------------------
// One row-slot, 2 batch lanes. Packed gather (ascending j, round-1 op order),
// d update, 8-branch shuffle sum, leader mem/spike update.
template<int G, bool F32>
__device__ __forceinline__ void slot_compute(
    int r, const float4* __restrict__ vw, const uint2* __restrict__ vc,
    const uint8_t* __restrict__ ktab,
    float bt, float bias, float al,
    float (&dreg)[2], uint8_t (*s_l)[2], float (*mem_l)[2])
{
  float a0 = bias, a1 = bias;
  const float4* vwr = vw + r;
  const uint2*  vcr = vc + r;
#pragma unroll
  for (int g = 0; g < G; ++g) {
    const float4 w = vwr[g * ROWS];
    const uint2  c = vcr[g * ROWS];
    if constexpr (F32) {
      { const float2 kv = *(const float2*)(ktab + (c.x & 0xffffu));
        a0 = fmaf(w.x, kv.x, a0); a1 = fmaf(w.x, kv.y, a1); }
      { const float2 kv = *(const float2*)(ktab + (c.x >> 16));
        a0 = fmaf(w.y, kv.x, a0); a1 = fmaf(w.y, kv.y, a1); }
      { const float2 kv = *(const float2*)(ktab + (c.y & 0xffffu));
        a0 = fmaf(w.z, kv.x, a0); a1 = fmaf(w.z, kv.y, a1); }
      { const float2 kv = *(const float2*)(ktab + (c.y >> 16));
        a0 = fmaf(w.w, kv.x, a0); a1 = fmaf(w.w, kv.y, a1); }
    } else {
      { const uint32_t q = *(const uint16_t*)(ktab + (c.x & 0xffffu));
        a0 = fmaf(w.x, (float)(q & 0xffu), a0); a1 = fmaf(w.x, (float)(q >> 8), a1); }
      { const uint32_t q = *(const uint16_t*)(ktab + (c.x >> 16));
        a0 = fmaf(w.y, (float)(q & 0xffu), a0); a1 = fmaf(w.y, (float)(q >> 8), a1); }
      { const uint32_t q = *(const uint16_t*)(ktab + (c.y & 0xffffu));
        a0 = fmaf(w.z, (float)(q & 0xffu), a0); a1 = fmaf(w.z, (float)(q >> 8), a1); }
      { const uint32_t q = *(const uint16_t*)(ktab + (c.y >> 16));
        a0 = fmaf(w.w, (float)(q & 0xffu), a0); a1 = fmaf(w.w, (float)(q >> 8), a1); }
    }
  }
  const float ob = 1.0f - bt;
  float d0 = fmaf(bt, dreg[0], ob * a0);
  float d1 = fmaf(bt, dreg[1], ob * a1);
  dreg[0] = d0; dreg[1] = d1;
  d0 += __shfl_xor(d0, 1); d0 += __shfl_xor(d0, 2); d0 += __shfl_xor(d0, 4);
  d1 += __shfl_xor(d1, 1); d1 += __shfl_xor(d1, 2); d1 += __shfl_xor(d1, 4);
  if ((threadIdx.x & 7) == 0) {
    const int n = r >> 3;
    const float oa = 1.0f - al;
    float2 mv = *reinterpret_cast<float2*>(&mem_l[n][0]);
    const uint32_t so = *reinterpret_cast<uint16_t*>(&s_l[n][0]);
    const float m0 = fmaf(mv.x - (float)(so & 0xffu), al, oa * d0);
    const float m1 = fmaf(mv.y - (float)(so >> 8),    al, oa * d1);
    *reinterpret_cast<float2*>(&mem_l[n][0]) = make_float2(m0, m1);
    const uint16_t sn = (uint16_t)((m0 > 1.0f ? 1u : 0u) | (m1 > 1.0f ? 0x100u : 0u));
    *reinterpret_cast<uint16_t*>(&s_l[n][0]) = sn;
  }
}

// ---------------------------------------------------------------------------
// Main kernel: 512 blocks x 512 threads, 2 batches/block.
// __launch_bounds__(512, 2): the ONLY config observed to compile this state
// set at 128 VGPRs with zero spill (rounds 1/3; FETCH ~30 MB). Requesting 4
// waves/EU halves the budget to 64 VGPRs and spills ~1KB/thread (rounds 5-7,
// FETCH 28-70 GB). At 128 VGPRs the HW still co-schedules 2 blocks/CU
// (4 waves/SIMD x 128 regs = full 512-reg file) -> 16 waves/CU.
// Row slots: r = tid, tid+512, tid+1024 (all threads); rows 1536-1599 on
// wave 7 (tid>=448). Readout on wave 0 -> balanced.
// ---------------------------------------------------------------------------
__global__ void __launch_bounds__(NTHR, 2)
snn_main(const float* __restrict__ x,
         const float* __restrict__ b1, const float* __restrict__ tm1, const float* __restrict__ tn1,
         const float* __restrict__ b2, const float* __restrict__ tm2, const float* __restrict__ tn2,
         const float* __restrict__ b3, const float* __restrict__ tm3, const float* __restrict__ tn3,
         const float* __restrict__ W4, const float* __restrict__ b4, const float* __restrict__ tm4,
         const float4* __restrict__ w1v, const uint2* __restrict__ w1c,
         const float4* __restrict__ w2v, const uint2* __restrict__ w2c,
         const float4* __restrict__ w3v, const uint2* __restrict__ w3c,
         float* __restrict__ out)
{
  __shared__ __align__(16) float   k1f[320][2];       // L1 input (x f32 + s1-as-f32)
  __shared__ __align__(4)  uint8_t k23[400][2];       // L2/3 input (binary spikes u8)
  __shared__ __align__(4)  uint8_t s_lds[3][200][2];
  __shared__ __align__(16) float   mem_lds[3][200][2];
  __shared__ float w4_lds[12][201];

  const int tid = threadIdx.x;
  const int bg  = blockIdx.x;          // batches bg*2, bg*2+1

  for (int idx = tid; idx < 300; idx += NTHR) {
    reinterpret_cast<uint32_t*>(&s_lds[0][0][0])[idx] = 0u;
    reinterpret_cast<float4*>(&mem_lds[0][0][0])[idx] = make_float4(0.f, 0.f, 0.f, 0.f);
  }
  for (int idx = tid; idx < 12 * 200; idx += NTHR)
    w4_lds[idx / 200][idx % 200] = W4[idx];

  // per-thread constants: 3 layers x 4 slots (slot 3 used only by wave 7)
  const int r3 = 1536 + (tid & 63);
  float beta_[3][4], bias_[3][4], alpha_[3][4];
#pragma unroll
  for (int i = 0; i < 4; ++i) {
    const int r = (i < 3) ? (tid + NTHR * i) : r3;
    const int n = r >> 3;
    beta_[0][i] = sigmoidf(tn1[r]); bias_[0][i] = b1[r]; alpha_[0][i] = sigmoidf(tm1[n]);
    beta_[1][i] = sigmoidf(tn2[r]); bias_[1][i] = b2[r]; alpha_[1][i] = sigmoidf(tm2[n]);
    beta_[2][i] = sigmoidf(tn3[r]); bias_[2][i] = b3[r]; alpha_[2][i] = sigmoidf(tm3[n]);
  }

  float d_[3][4][2];
#pragma unroll
  for (int l = 0; l < 3; ++l)
#pragma unroll
    for (int i = 0; i < 4; ++i)
#pragma unroll
      for (int b = 0; b < 2; ++b) d_[l][i][b] = 0.0f;

  // x staging addresses hoisted out of the T-loop (2 batches x 120 feats)
  const float* xp = nullptr; float* kdst = nullptr;
  if (tid < 240) {
    const int bat = tid / 120, cf = tid - bat * 120;
    const int c = cf / 40, f = cf - c * 40;
    xp = x + (((size_t)(bg * 2 + bat) * 3 + c) * T_STEPS) * 40 + f;
    kdst = &k1f[cf][bat];
  }

  float m4_reg = 0.0f, m4_acc = 0.0f, a4 = 0.0f, b4r = 0.0f;
  if (tid < 24) { const int o = tid >> 1; a4 = sigmoidf(tm4[o]); b4r = b4[o]; }
  __syncthreads();

  const uint8_t* k1b = reinterpret_cast<const uint8_t*>(&k1f[0][0]);
  const uint8_t* k2b = reinterpret_cast<const uint8_t*>(&k23[0][0]);

  for (int t = 0; t < T_STEPS; ++t) {
    // ---- stage k1 = [x_t | s1(old) as f32] ----------------------------
    if (tid < 240) *kdst = xp[t * 40];
    if (tid < 200) {
      const uint32_t so = *reinterpret_cast<const uint16_t*>(&s_lds[0][tid][0]);
      *reinterpret_cast<float2*>(&k1f[120 + tid][0]) =
          make_float2((float)(so & 0xffu), (float)(so >> 8));
    }
    __syncthreads();
    slot_compute<G1, true>(tid, w1v, w1c, k1b,
                           beta_[0][0], bias_[0][0], alpha_[0][0],
                           d_[0][0], s_lds[0], mem_lds[0]);
    slot_compute<G1, true>(tid + 512, w1v, w1c, k1b,
                           beta_[0][1], bias_[0][1], alpha_[0][1],
                           d_[0][1], s_lds[0], mem_lds[0]);
    slot_compute<G1, true>(tid + 1024, w1v, w1c, k1b,
                           beta_[0][2], bias_[0][2], alpha_[0][2],
                           d_[0][2], s_lds[0], mem_lds[0]);
    if (tid >= 448)
      slot_compute<G1, true>(r3, w1v, w1c, k1b,
                             beta_[0][3], bias_[0][3], alpha_[0][3],
                             d_[0][3], s_lds[0], mem_lds[0]);
    __syncthreads();
    // ---- stage k2 = [s1(new) | s2(old)] (u32 copies: 100+100 words) ---
    if (tid < 100)
      reinterpret_cast<uint32_t*>(&k23[0][0])[tid] =
          reinterpret_cast<const uint32_t*>(&s_lds[0][0][0])[tid];
    else if (tid < 200)
      reinterpret_cast<uint32_t*>(&k23[0][0])[tid] =
          reinterpret_cast<const uint32_t*>(&s_lds[1][0][0])[tid - 100];
    __syncthreads();
    slot_compute<G23, false>(tid, w2v, w2c, k2b,
                             beta_[1][0], bias_[1][0], alpha_[1][0],
                             d_[1][0], s_lds[1], mem_lds[1]);
    slot_compute<G23, false>(tid + 512, w2v, w2c, k2b,
                             beta_[1][1], bias_[1][1], alpha_[1][1],
                             d_[1][1], s_lds[1], mem_lds[1]);
    slot_compute<G23, false>(tid + 1024, w2v, w2c, k2b,
                             beta_[1][2], bias_[1][2], alpha_[1][2],
                             d_[1][2], s_lds[1], mem_lds[1]);
    if (tid >= 448)
      slot_compute<G23, false>(r3, w2v, w2c, k2b,
                               beta_[1][3], bias_[1][3], alpha_[1][3],
                               d_[1][3], s_lds[1], mem_lds[1]);
    __syncthreads();
    // ---- stage k3 = [s2(new) | s3(old)] -------------------------------
    if (tid < 100)
      reinterpret_cast<uint32_t*>(&k23[0][0])[tid] =
          reinterpret_cast<const uint32_t*>(&s_lds[1][0][0])[tid];
    else if (tid < 200)
      reinterpret_cast<uint32_t*>(&k23[0][0])[tid] =
          reinterpret_cast<const uint32_t*>(&s_lds[2][0][0])[tid - 100];
    __syncthreads();
    slot_compute<G23, false>(tid, w3v, w3c, k2b,
                             beta_[2][0], bias_[2][0], alpha_[2][0],
                             d_[2][0], s_lds[2], mem_lds[2]);
    slot_compute<G23, false>(tid + 512, w3v, w3c, k2b,
                             beta_[2][1], bias_[2][1], alpha_[2][1],
                             d_[2][1], s_lds[2], mem_lds[2]);
    slot_compute<G23, false>(tid + 1024, w3v, w3c, k2b,
                             beta_[2][2], bias_[2][2], alpha_[2][2],
                             d_[2][2], s_lds[2], mem_lds[2]);
    if (tid >= 448)
      slot_compute<G23, false>(r3, w3v, w3c, k2b,
                               beta_[2][3], bias_[2][3], alpha_[2][3],
                               d_[2][3], s_lds[2], mem_lds[2]);
    __syncthreads();
    // ---- leaky readout (wave 0; overlaps next step's staging) ---------
    if (tid < 24) {
      const int o = tid >> 1, bat = tid & 1;
      float dot = b4r;
#pragma unroll 8
      for (int n = 0; n < 200; ++n)
        dot = fmaf(w4_lds[o][n], (float)s_lds[2][n][bat], dot);
      m4_reg = a4 * m4_reg + (1.0f - a4) * dot;
      m4_acc += m4_reg;
    }
    // no trailing barrier: stage-k1(t+1) touches only k1f / s_lds[0]
  }

  // ---- log_softmax(acc / T) -------------------------------------------
  __syncthreads();
  if (tid < 24) {
    const int o = tid >> 1, bat = tid & 1;
    k1f[o][bat] = m4_acc * (1.0f / (float)T_STEPS);
  }
  __syncthreads();
  if (tid < 2) {
    const int bat = tid;
    float v[12], mx = -1e30f;
#pragma unroll
    for (int o = 0; o < 12; ++o) { v[o] = k1f[o][bat]; mx = fmaxf(mx, v[o]); }
    float s = 0.0f;
#pragma unroll
    for (int o = 0; o < 12; ++o) s += expf(v[o] - mx);
    const float ls = logf(s);
#pragma unroll
    for (int o = 0; o < 12; ++o)
      out[((size_t)(bg * 2 + bat)) * 12 + o] = v[o] - mx - ls;
  }
}

// ---------------------------------------------------------------------------
extern "C" void kernel_launch(void* const* d_in, const int* in_sizes, int n_in,
                              void* d_out, int out_size, void* d_ws, size_t ws_size,
                              hipStream_t stream) {
  (void)in_sizes; (void)n_in; (void)out_size; (void)ws_size;
  const float* x   = (const float*)d_in[0];
  const float* W1  = (const float*)d_in[1];
  const float* b1  = (const float*)d_in[2];
  const float* tm1 = (const float*)d_in[3];
  const float* tn1 = (const float*)d_in[4];
  const float* W2  = (const float*)d_in[5];
  const float* b2  = (const float*)d_in[6];
  const float* tm2 = (const float*)d_in[7];
  const float* tn2 = (const float*)d_in[8];
  const float* W3  = (const float*)d_in[9];
  const float* b3  = (const float*)d_in[10];
  const float* tm3 = (const float*)d_in[11];
  const float* tn3 = (const float*)d_in[12];
  const float* W4  = (const float*)d_in[13];
  const float* b4  = (const float*)d_in[14];
  const float* tm4 = (const float*)d_in[15];

  uint8_t* ws = (uint8_t*)d_ws;
  const float4* w1v = (const float4*)(ws + W1V_OFF);
  const float4* w2v = (const float4*)(ws + W2V_OFF);
  const float4* w3v = (const float4*)(ws + W3V_OFF);
  const uint2*  w1c = (const uint2*)(ws + W1C_OFF);
  const uint2*  w2c = (const uint2*)(ws + W2C_OFF);
  const uint2*  w3c = (const uint2*)(ws + W3C_OFF);

  prep_kernel<<<dim3(19), dim3(256), 0, stream>>>(W1, W2, W3, ws);
  snn_main<<<dim3(NBLK), dim3(NTHR), 0, stream>>>(
      x, b1, tm1, tn1, b2, tm2, tn2, b3, tm3, tn3, W4, b4, tm4,
      w1v, w1c, w2v, w2c, w3v, w3c, (float*)d_out);
}

// Round 9
// 5656.631 us; speedup vs baseline: 9.6606x; 9.6606x over previous
//
#include <hip/hip_runtime.h>
#include <stdint.h>

#define T_STEPS 101
#define ROWS 1600
#define NTHR 512
#define NBLK 512            /* 2 batches per block, 1024 batches total */
#define NZ1 40
#define NZ2 50
#define OFF2 (NZ1 * ROWS)              /* 64000  */
#define OFF3 (OFF2 + NZ2 * ROWS)       /* 144000 */
#define NZTOT (OFF3 + NZ2 * ROWS)      /* 224000 */

__device__ __forceinline__ float sigmoidf(float v) { return 1.0f / (1.0f + expf(-v)); }

// ---------------------------------------------------------------------------
// Prep: round-1's verified fixed-length CSR. SoA vals[j*1600+r] / u16 cols.
// ---------------------------------------------------------------------------
__global__ void prep_kernel(const float* __restrict__ W1, const float* __restrict__ W2,
                            const float* __restrict__ W3,
                            float* __restrict__ vals, uint16_t* __restrict__ cols) {
  int gid = blockIdx.x * blockDim.x + threadIdx.x;
  if (gid >= 3 * ROWS) return;
  int l = gid / ROWS, r = gid - l * ROWS;
  const float* W; int in_f, knz, off;
  if (l == 0)      { W = W1; in_f = 320; knz = NZ1; off = 0;    }
  else if (l == 1) { W = W2; in_f = 400; knz = NZ2; off = OFF2; }
  else             { W = W3; in_f = 400; knz = NZ2; off = OFF3; }
  float* v = vals + off;
  uint16_t* c = cols + off;
  int cnt = 0;
  for (int col = 0; col < in_f; ++col) {
    float w = W[(size_t)r * in_f + col];
    if (w != 0.0f) {
      if (cnt < knz) { v[cnt * ROWS + r] = w; c[cnt * ROWS + r] = (uint16_t)col; }
      ++cnt;
    }
  }
  for (; cnt < knz; ++cnt) { v[cnt * ROWS + r] = 0.0f; c[cnt * ROWS + r] = 0; }
}

// ---------------------------------------------------------------------------
// One layer's step for this thread's row slots -- EXACT round-1 structure,
// narrowed from 4 to 2 batch lanes. Scalar w/col loads, unroll 10 (the only
// code shape proven spill-free at 128 VGPRs on this toolchain).
// Rows: slot i<3 -> r = tid + 512*i ; slot 3 -> r = 1536 + tid (wave 0 only).
// ---------------------------------------------------------------------------
template<int L, int KNZ, bool U8>
__device__ __forceinline__ void layer_step(
    int tid,
    const float* __restrict__ vals, const uint16_t* __restrict__ cols,
    float (&d)[3][4][2],
    const float (&beta)[3][4], const float (&bia)[3][4], const float (&alpha)[3][4],
    const float (*k1f)[2], const uint8_t (*k23)[2],
    uint8_t (*s_l)[2], float (*mem_l)[2])
{
#pragma unroll
  for (int i = 0; i < 4; ++i) {
    if (i == 3 && tid >= 64) break;          // wave-uniform: only wave 0 has slot 3
    const int r = (i < 3) ? (tid + NTHR * i) : (1536 + tid);
    float a0 = bia[L][i], a1 = a0;
    const float* vp = vals + r;
    const uint16_t* cp = cols + r;
#pragma unroll 10
    for (int j = 0; j < KNZ; ++j) {
      const float w = vp[(size_t)j * ROWS];
      const int c = cp[(size_t)j * ROWS];
      if constexpr (U8) {
        const uint32_t s2 = *reinterpret_cast<const uint16_t*>(k23[c]);
        a0 = fmaf(w, (float)(s2 & 0xffu), a0);
        a1 = fmaf(w, (float)(s2 >> 8), a1);
      } else {
        const float2 kv = *reinterpret_cast<const float2*>(k1f[c]);
        a0 = fmaf(w, kv.x, a0);
        a1 = fmaf(w, kv.y, a1);
      }
    }
    // d = beta*d + (1-beta)*ff
    const float bt = beta[L][i], ob = 1.0f - bt;
    float d0 = fmaf(bt, d[L][i][0], ob * a0);
    float d1 = fmaf(bt, d[L][i][1], ob * a1);
    d[L][i][0] = d0; d[L][i][1] = d1;
    // branch sum over the neuron's 8 rows (8 consecutive, 8-aligned lanes)
    d0 += __shfl_xor(d0, 1); d0 += __shfl_xor(d0, 2); d0 += __shfl_xor(d0, 4);
    d1 += __shfl_xor(d1, 1); d1 += __shfl_xor(d1, 2); d1 += __shfl_xor(d1, 4);
    if ((tid & 7) == 0) {
      const int n = r >> 3;
      const float al = alpha[L][i], oa = 1.0f - al;
      float2 mv = *reinterpret_cast<float2*>(&mem_l[n][0]);
      const uint32_t so = *reinterpret_cast<uint16_t*>(&s_l[n][0]);
      // mem = (mem - vth*spike)*alpha + (1-alpha)*sum(d)
      const float m0 = fmaf(mv.x - (float)(so & 0xffu), al, oa * d0);
      const float m1 = fmaf(mv.y - (float)(so >> 8),    al, oa * d1);
      *reinterpret_cast<float2*>(&mem_l[n][0]) = make_float2(m0, m1);
      const uint16_t sn = (uint16_t)((m0 > 1.0f ? 1u : 0u) | (m1 > 1.0f ? 0x100u : 0u));
      *reinterpret_cast<uint16_t*>(&s_l[n][0]) = sn;
    }
  }
}

// ---------------------------------------------------------------------------
// Main kernel: 512 blocks x 512 threads, 2 batches/block. Exact round-1
// structure (verified spill-free, absmax 0.0) narrowed to 2 batch lanes so
// two blocks can co-reside per CU (16 waves/CU latency hiding).
// ---------------------------------------------------------------------------
__global__ void __launch_bounds__(NTHR, 2)
snn_main(const float* __restrict__ x,
         const float* __restrict__ b1, const float* __restrict__ tm1, const float* __restrict__ tn1,
         const float* __restrict__ b2, const float* __restrict__ tm2, const float* __restrict__ tn2,
         const float* __restrict__ b3, const float* __restrict__ tm3, const float* __restrict__ tn3,
         const float* __restrict__ W4, const float* __restrict__ b4, const float* __restrict__ tm4,
         const float* __restrict__ vals, const uint16_t* __restrict__ cols,
         float* __restrict__ out)
{
  __shared__ __align__(16) float   k1f[320][2];       // layer-1 input (x + s1-as-f32)
  __shared__ __align__(4)  uint8_t k23[400][2];       // layer-2/3 input (binary spikes)
  __shared__ __align__(4)  uint8_t s_lds[3][200][2];  // spike state (exact 0/1)
  __shared__ __align__(16) float   mem_lds[3][200][2];
  __shared__ float w4_lds[12][201];

  const int tid = threadIdx.x;
  const int bg  = blockIdx.x;          // batches bg*2, bg*2+1

  // zero states: s = 1200 B (300 u32), mem = 4800 B (300 float4)
  for (int idx = tid; idx < 300; idx += NTHR) {
    reinterpret_cast<uint32_t*>(&s_lds[0][0][0])[idx] = 0u;
    reinterpret_cast<float4*>(&mem_lds[0][0][0])[idx] = make_float4(0.f, 0.f, 0.f, 0.f);
  }
  for (int idx = tid; idx < 12 * 200; idx += NTHR)
    w4_lds[idx / 200][idx % 200] = W4[idx];

  float d[3][4][2];
#pragma unroll
  for (int l = 0; l < 3; ++l)
#pragma unroll
    for (int i = 0; i < 4; ++i)
#pragma unroll
      for (int b = 0; b < 2; ++b) d[l][i][b] = 0.0f;

  float beta[3][4], bia[3][4], alpha[3][4];
#pragma unroll
  for (int i = 0; i < 4; ++i) {
    const int r = (i < 3) ? (tid + NTHR * i) : (1536 + (tid & 63));
    const int n = r >> 3;
    beta[0][i] = sigmoidf(tn1[r]); bia[0][i] = b1[r]; alpha[0][i] = sigmoidf(tm1[n]);
    beta[1][i] = sigmoidf(tn2[r]); bia[1][i] = b2[r]; alpha[1][i] = sigmoidf(tm2[n]);
    beta[2][i] = sigmoidf(tn3[r]); bia[2][i] = b3[r]; alpha[2][i] = sigmoidf(tm3[n]);
  }

  float m4_reg = 0.0f, m4_acc = 0.0f, a4 = 0.0f, b4r = 0.0f;
  if (tid < 24) { const int o = tid >> 1; a4 = sigmoidf(tm4[o]); b4r = b4[o]; }
  __syncthreads();

  for (int t = 0; t < T_STEPS; ++t) {
    // ---- build k1 = [x_t | s1(old)] -----------------------------------
    if (tid < 240) {
      const int bat = tid / 120, cf = tid - bat * 120;
      const int c = cf / 40, f = cf - c * 40;
      const int b = bg * 2 + bat;
      k1f[cf][bat] = x[(((size_t)b * 3 + c) * T_STEPS + t) * 40 + f];
    }
    if (tid < 200) {
      const uint32_t so = *reinterpret_cast<const uint16_t*>(&s_lds[0][tid][0]);
      *reinterpret_cast<float2*>(&k1f[120 + tid][0]) =
          make_float2((float)(so & 0xffu), (float)(so >> 8));
    }
    __syncthreads();
    layer_step<0, NZ1, false>(tid, vals, cols, d, beta, bia, alpha,
                              k1f, k23, s_lds[0], mem_lds[0]);
    __syncthreads();
    // ---- build k2 = [s1(new) | s2(old)] (u32 copies: 100+100 words) ---
    if (tid < 100)
      reinterpret_cast<uint32_t*>(&k23[0][0])[tid] =
          reinterpret_cast<const uint32_t*>(&s_lds[0][0][0])[tid];
    else if (tid < 200)
      reinterpret_cast<uint32_t*>(&k23[0][0])[tid] =
          reinterpret_cast<const uint32_t*>(&s_lds[1][0][0])[tid - 100];
    __syncthreads();
    layer_step<1, NZ2, true>(tid, vals + OFF2, cols + OFF2, d, beta, bia, alpha,
                             k1f, k23, s_lds[1], mem_lds[1]);
    __syncthreads();
    // ---- build k3 = [s2(new) | s3(old)] -------------------------------
    if (tid < 100)
      reinterpret_cast<uint32_t*>(&k23[0][0])[tid] =
          reinterpret_cast<const uint32_t*>(&s_lds[1][0][0])[tid];
    else if (tid < 200)
      reinterpret_cast<uint32_t*>(&k23[0][0])[tid] =
          reinterpret_cast<const uint32_t*>(&s_lds[2][0][0])[tid - 100];
    __syncthreads();
    layer_step<2, NZ2, true>(tid, vals + OFF3, cols + OFF3, d, beta, bia, alpha,
                             k1f, k23, s_lds[2], mem_lds[2]);
    __syncthreads();
    // ---- leaky readout ------------------------------------------------
    if (tid < 24) {
      const int o = tid >> 1, bat = tid & 1;
      float dot = b4r;
#pragma unroll 8
      for (int n = 0; n < 200; ++n)
        dot = fmaf(w4_lds[o][n], (float)s_lds[2][n][bat], dot);
      m4_reg = a4 * m4_reg + (1.0f - a4) * dot;
      m4_acc += m4_reg;
    }
    __syncthreads();
  }

  // ---- log_softmax(acc / T) -------------------------------------------
  if (tid < 24) {
    const int o = tid >> 1, bat = tid & 1;
    k1f[o][bat] = m4_acc * (1.0f / (float)T_STEPS);
  }
  __syncthreads();
  if (tid < 2) {
    const int bat = tid;
    float v[12], mx = -1e30f;
#pragma unroll
    for (int o = 0; o < 12; ++o) { v[o] = k1f[o][bat]; mx = fmaxf(mx, v[o]); }
    float s = 0.0f;
#pragma unroll
    for (int o = 0; o < 12; ++o) s += expf(v[o] - mx);
    const float ls = logf(s);
#pragma unroll
    for (int o = 0; o < 12; ++o)
      out[((size_t)(bg * 2 + bat)) * 12 + o] = v[o] - mx - ls;
  }
}

// ---------------------------------------------------------------------------
extern "C" void kernel_launch(void* const* d_in, const int* in_sizes, int n_in,
                              void* d_out, int out_size, void* d_ws, size_t ws_size,
                              hipStream_t stream) {
  (void)in_sizes; (void)n_in; (void)out_size; (void)ws_size;
  const float* x   = (const float*)d_in[0];
  const float* W1  = (const float*)d_in[1];
  const float* b1  = (const float*)d_in[2];
  const float* tm1 = (const float*)d_in[3];
  const float* tn1 = (const float*)d_in[4];
  const float* W2  = (const float*)d_in[5];
  const float* b2  = (const float*)d_in[6];
  const float* tm2 = (const float*)d_in[7];
  const float* tn2 = (const float*)d_in[8];
  const float* W3  = (const float*)d_in[9];
  const float* b3  = (const float*)d_in[10];
  const float* tm3 = (const float*)d_in[11];
  const float* tn3 = (const float*)d_in[12];
  const float* W4  = (const float*)d_in[13];
  const float* b4  = (const float*)d_in[14];
  const float* tm4 = (const float*)d_in[15];

  float*    vals = (float*)d_ws;                                     // 224000 floats
  uint16_t* cols = (uint16_t*)((char*)d_ws + (size_t)NZTOT * 4);     // 224000 u16

  prep_kernel<<<dim3(19), dim3(256), 0, stream>>>(W1, W2, W3, vals, cols);
  snn_main<<<dim3(NBLK), dim3(NTHR), 0, stream>>>(
      x, b1, tm1, tn1, b2, tm2, tn2, b3, tm3, tn3, W4, b4, tm4,
      vals, cols, (float*)d_out);
}